// Round 6
// baseline (286.621 us; speedup 1.0000x reference)
//
#include <hip/hip_runtime.h>
#include <hip/hip_bf16.h>

// GAT encoder, fused, bf16-MFMA. B=8192 graphs, N=64, F=64. 4 waves/block,
// 5 blocks/CU (LDS 32256 B).
//
// R6 = R5 resubmit (container infra failure) with robustness fixes:
//  - exp2f instead of __builtin_amdgcn_exp2f (portability).
//  - wt rows 72..79 zeroed once (score B-frag reads them; only unconsumed
//    C-columns, but zero for determinism).
//
// Design:
//  - Scores via MFMA: prep computes wa = W@a_src, wd = W@a_dst per head and
//    appends them as B-columns 64.. of the weight image; the h@W MFMA's 5th
//    C-block yields all src/dst scores (s = h@(W a) = (h@W) a).
//  - Softmax factorized: e = exp2(lrelu(s'+d')) = (p>=1 ? p : esn*edn),
//    p = esp*edp, esp=2^s', esn=2^(0.2 s') (log2 domain, clamp 63 guards the
//    invisible-row garbage path; 63+63 < 128 keeps everything finite).
//    Masked col m: edp=edn=0 -> e=0 exactly. Fully-masked row (mymask=0):
//    e = fma(e_sel, 0, 1) = 1 for all m -> uniform 1/64 as in reference.
//    Row factors ride in h/hp pad columns (f32), col factors in the
//    norm-scratch alias dsc[8][64].
//  - Norms register-carried (norm0 fused with x load; norm1 reads hb once).
//  - denv/sarr/darr/asv/adv/bias LDS arrays gone (shfl + registers).
//
// Fragment layouts (gfx950 16x16x32 bf16):
//   A[m][k]: m=lane&15, k=(lane>>4)*8+j ; B[k][n]: n=lane&15, same k
//   C/D[r]: col=lane&15, row=(lane>>4)*4+r

typedef __attribute__((ext_vector_type(8))) short bf16x8;
typedef __attribute__((ext_vector_type(4))) float f32x4;

#define MFMA_B16 __builtin_amdgcn_mfma_f32_16x16x32_bf16

__device__ __forceinline__ unsigned short f2b(float f) {
    return __builtin_bit_cast(unsigned short, __float2bfloat16(f));
}
__device__ __forceinline__ float b2f(unsigned short s) {
    unsigned u = ((unsigned)s) << 16;
    return __builtin_bit_cast(float, u);
}

// ---- prep: per-layer 72x64 bf16 weight images in d_ws ----
// L0 (ws+0):    rows 0..63 = W0^T concat ([h*16+o][f]); 64..67 = wa0[h][f];
//               68..71 = wd0[h][f]
// L1 (ws+4608): rows 0..63 = W1^T ([o][f]); 64 = wa1[f]; 65 = wd1[f]; 66..71 = 0
__global__ __launch_bounds__(256) void prep_weights(
    const float* __restrict__ w0g, const float* __restrict__ as0,
    const float* __restrict__ ad0, const float* __restrict__ w1g,
    const float* __restrict__ as1, const float* __restrict__ ad1,
    unsigned short* __restrict__ ws)
{
    const int tid = threadIdx.x;
    #pragma unroll
    for (int k = 0; k < 16; ++k) {
        int idx = k * 256 + tid;                 // w0: [4][64][16]
        int hh = idx >> 10, f = (idx >> 4) & 63, o = idx & 15;
        ws[(hh * 16 + o) * 64 + f] = f2b(w0g[idx]);
        int f1 = idx >> 6, o1 = idx & 63;        // w1: [64][64]
        ws[4608 + o1 * 64 + f1] = f2b(w1g[idx]);
    }
    if (tid < 64) {
        const int f = tid;
        #pragma unroll
        for (int h = 0; h < 4; ++h) {
            float sa = 0.f, sd = 0.f;
            #pragma unroll
            for (int o = 0; o < 16; ++o) {
                float w = w0g[(h * 64 + f) * 16 + o];
                sa = fmaf(w, as0[h * 16 + o], sa);
                sd = fmaf(w, ad0[h * 16 + o], sd);
            }
            ws[(64 + h) * 64 + f] = f2b(sa);
            ws[(68 + h) * 64 + f] = f2b(sd);
        }
        float sa = 0.f, sd = 0.f;
        #pragma unroll
        for (int o = 0; o < 64; ++o) {
            float w = w1g[f * 64 + o];
            sa = fmaf(w, as1[o], sa);
            sd = fmaf(w, ad1[o], sd);
        }
        ws[4608 + 64 * 64 + f] = f2b(sa);
        ws[4608 + 65 * 64 + f] = f2b(sd);
        for (int r = 66; r < 72; ++r) ws[4608 + r * 64 + f] = 0;
    }
}

__global__ __launch_bounds__(256, 5) void gat_fused(
    const float* __restrict__ x, const int* __restrict__ fhi,
    const unsigned short* __restrict__ wsb,
    const float* __restrict__ b0g, const float* __restrict__ b1g,
    float* __restrict__ out)
{
    const int b = blockIdx.x;
    const int scene = b >> 3;
    const int tt = b & 7;
    const int tid = threadIdx.x;
    const int lane = tid & 63;
    const int wv = tid >> 6;
    const int lg = lane >> 4;
    const int li = lane & 15;
    const int R = 16 * wv + li;          // this lane's attention row
    constexpr float L2E = 1.44269504f;

    // pads: hb[n][64+2h] (f32) = esp row factors; hpt[n][64+2h] = esn.
    __shared__ __align__(16) unsigned short hb [64][72];   //  9216 B
    __shared__ __align__(16) unsigned short wt [80][72];   // 11520 B
    __shared__ __align__(16) unsigned short hpt[64][72];   //  9216 B
    __shared__ float dsc[8][64];   // norm scratch ALIAS col factors edp[h]/edn[h]
    __shared__ float maskv[64];    // total 32256 B

    // ---- per-thread constants (registers) ----
    const float b0r = b0g[li];
    const float b1r[4] = {b1g[li], b1g[16 + li], b1g[32 + li], b1g[48 + li]};
    const float mymask = (fhi[scene * 64 + R] <= tt) ? 1.0f : 0.0f;
    const float base = 1.0f - mymask;
    if (tid < 64) maskv[tid] = (fhi[scene * 64 + tid] <= tt) ? 1.0f : 0.0f;
    // zero wt rows 72..79 once (score B-frags read them; unconsumed outputs)
    if (tid < 72) {
        int row = 72 + tid / 9, c8 = (tid % 9) * 8;
        *(uint4*)&wt[row][c8] = make_uint4(0, 0, 0, 0);
    }
    __syncthreads();

    float invcnt = 0.f;
    if (tid < 64) {
        float c = 0.f;
        #pragma unroll
        for (int m = 0; m < 64; ++m) c += maskv[m];
        invcnt = 1.0f / fmaxf(c, 1.0f);
    }

    // ---- stage x into registers + W0 image; fused masked-norm pass 1 ----
    float xv[16];
    {
        const float* xb = x + (size_t)b * 4096;
        #pragma unroll
        for (int k = 0; k < 16; ++k) xv[k] = xb[(4 * k + wv) * 64 + lane];
        { int e = tid * 8;         *(uint4*)&wt[e >> 6][e & 63] = *(const uint4*)(wsb + e); }
        { int e = (tid + 256) * 8; *(uint4*)&wt[e >> 6][e & 63] = *(const uint4*)(wsb + e); }
        if (tid < 64) { int e = (tid + 512) * 8; *(uint4*)&wt[e >> 6][e & 63] = *(const uint4*)(wsb + e); }
        float s = 0.f, q = 0.f;
        #pragma unroll
        for (int k = 0; k < 16; ++k) {
            float mv = maskv[4 * k + wv];        // wave-uniform broadcast read
            float xm = xv[k] * mv;
            s += xm;
            q = fmaf(xm, xv[k], q);
        }
        dsc[wv][lane] = s;
        dsc[4 + wv][lane] = q;
    }
    __syncthreads();

    auto norm_combine = [&]() {
        if (tid < 64) {
            float sum = dsc[0][tid] + dsc[1][tid] + dsc[2][tid] + dsc[3][tid];
            float ssq = dsc[4][tid] + dsc[5][tid] + dsc[6][tid] + dsc[7][tid];
            float mean = sum * invcnt;
            float var = fmaxf(ssq * invcnt - mean * mean, 0.f);
            dsc[0][tid] = mean;
            dsc[1][tid] = rsqrtf(var + 1e-5f);
        }
        __syncthreads();
    };
    norm_combine();
    {   // normalize from registers, write bf16 h
        float mean = dsc[0][lane], rstd = dsc[1][lane];
        #pragma unroll
        for (int k = 0; k < 16; ++k)
            hb[4 * k + wv][lane] = f2b((xv[k] - mean) * rstd);
    }
    __syncthreads();

    // ---- norm for layer 1 (reads hb once, register-carried) ----
    auto do_norm1 = [&]() {
        float hv[16], s = 0.f, q = 0.f;
        #pragma unroll
        for (int k = 0; k < 16; ++k) {
            hv[k] = b2f(hb[4 * k + wv][lane]);
            float xm = hv[k] * maskv[4 * k + wv];
            s += xm;
            q = fmaf(xm, hv[k], q);
        }
        dsc[wv][lane] = s;
        dsc[4 + wv][lane] = q;
        __syncthreads();
        norm_combine();
        float mean = dsc[0][lane], rstd = dsc[1][lane];
        #pragma unroll
        for (int k = 0; k < 16; ++k)
            hb[4 * k + wv][lane] = f2b((hv[k] - mean) * rstd);
        __syncthreads();
    };

    // ---- hp = h @ W (4 C-blocks -> hpt) + score C-block -> softmax factors ----
    auto do_matmul = [&](int layer) {
        const unsigned short* arow = &hb[R][0];
        bf16x8 a0 = *(const bf16x8*)(arow + 8 * lg);
        bf16x8 a1 = *(const bf16x8*)(arow + 32 + 8 * lg);
        #pragma unroll
        for (int c = 0; c < 4; ++c) {
            bf16x8 bv0 = *(const bf16x8*)&wt[16 * c + li][8 * lg];
            bf16x8 bv1 = *(const bf16x8*)&wt[16 * c + li][32 + 8 * lg];
            f32x4 acc = {0.f, 0.f, 0.f, 0.f};
            acc = MFMA_B16(a0, bv0, acc, 0, 0, 0);
            acc = MFMA_B16(a1, bv1, acc, 0, 0, 0);
            ushort4 pv;
            pv.x = f2b(acc[0]); pv.y = f2b(acc[1]);
            pv.z = f2b(acc[2]); pv.w = f2b(acc[3]);
            *(ushort4*)&hpt[16 * c + li][16 * wv + 4 * lg] = pv;
        }
        {   // score block: cols 64.. are s/d scores of rows 16wv+4lg+r
            bf16x8 bv0 = *(const bf16x8*)&wt[64 + li][8 * lg];
            bf16x8 bv1 = *(const bf16x8*)&wt[64 + li][32 + 8 * lg];
            f32x4 acc = {0.f, 0.f, 0.f, 0.f};
            acc = MFMA_B16(a0, bv0, acc, 0, 0, 0);
            acc = MFMA_B16(a1, bv1, acc, 0, 0, 0);
            const int smax = (layer == 0) ? 4 : 1;
            if (li < smax) {            // src-score producer, head li
                #pragma unroll
                for (int r = 0; r < 4; ++r) {
                    int row = 16 * wv + 4 * lg + r;
                    float sl2 = fminf(acc[r] * L2E, 63.f);
                    *(float*)&hb [row][64 + 2 * li] = exp2f(sl2);
                    *(float*)&hpt[row][64 + 2 * li] = exp2f(0.2f * sl2);
                }
            } else if (li < 2 * smax) {   // dst-score producer, head li-smax
                int h = li - smax;
                #pragma unroll
                for (int r = 0; r < 4; ++r) {
                    int row = 16 * wv + 4 * lg + r;
                    float mv = maskv[row];
                    float dl2 = fminf(acc[r] * L2E, 63.f);
                    dsc[h][row]     = (mv > 0.f) ? exp2f(dl2) : 0.f;
                    dsc[4 + h][row] = (mv > 0.f) ? exp2f(0.2f * dl2) : 0.f;
                }
            }
        }
        __syncthreads();
    };

    // ---- attention: factorized P in A-frag layout + aggregate MFMA ----
    auto do_attn = [&](int layer) {
        float esp[4], esn[4];
        const int nh = (layer == 0) ? 4 : 1;
        #pragma unroll
        for (int h = 0; h < 4; ++h) {
            if (h < nh) {
                esp[h] = *(const float*)&hb [R][64 + 2 * h];
                esn[h] = *(const float*)&hpt[R][64 + 2 * h];
            }
        }
        const f32x4 zero = {0.f, 0.f, 0.f, 0.f};
        f32x4 C0 = zero, C1 = zero, C2 = zero, C3 = zero;
        float den[4] = {0.f, 0.f, 0.f, 0.f};

        #pragma unroll
        for (int t = 0; t < 2; ++t) {
            const int mb = 32 * t + 8 * lg;
            if (layer == 0) {
                #pragma unroll
                for (int h = 0; h < 4; ++h) {
                    float dpv[8], dnv[8];
                    *(float4*)&dpv[0] = *(const float4*)&dsc[h][mb];
                    *(float4*)&dpv[4] = *(const float4*)&dsc[h][mb + 4];
                    *(float4*)&dnv[0] = *(const float4*)&dsc[4 + h][mb];
                    *(float4*)&dnv[4] = *(const float4*)&dsc[4 + h][mb + 4];
                    bf16x8 a;
                    #pragma unroll
                    for (int j = 0; j < 8; ++j) {
                        float p  = esp[h] * dpv[j];
                        float pn = esn[h] * dnv[j];
                        float e = (p >= 1.0f) ? p : pn;     // sign(s+d) test
                        e = fmaf(e, mymask, base);
                        den[h] += e;
                        a[j] = (short)f2b(e);
                    }
                    bf16x8 bv = *(const bf16x8*)&hpt[16 * h + li][mb];
                    if (h == 0) C0 = MFMA_B16(a, bv, C0, 0, 0, 0);
                    if (h == 1) C1 = MFMA_B16(a, bv, C1, 0, 0, 0);
                    if (h == 2) C2 = MFMA_B16(a, bv, C2, 0, 0, 0);
                    if (h == 3) C3 = MFMA_B16(a, bv, C3, 0, 0, 0);
                }
            } else {
                float dpv[8], dnv[8];
                *(float4*)&dpv[0] = *(const float4*)&dsc[0][mb];
                *(float4*)&dpv[4] = *(const float4*)&dsc[0][mb + 4];
                *(float4*)&dnv[0] = *(const float4*)&dsc[4][mb];
                *(float4*)&dnv[4] = *(const float4*)&dsc[4][mb + 4];
                bf16x8 a;
                #pragma unroll
                for (int j = 0; j < 8; ++j) {
                    float p  = esp[0] * dpv[j];
                    float pn = esn[0] * dnv[j];
                    float e = (p >= 1.0f) ? p : pn;
                    e = fmaf(e, mymask, base);
                    den[0] += e;
                    a[j] = (short)f2b(e);
                }
                bf16x8 bv0 = *(const bf16x8*)&hpt[li][mb];
                bf16x8 bv1 = *(const bf16x8*)&hpt[16 + li][mb];
                bf16x8 bv2 = *(const bf16x8*)&hpt[32 + li][mb];
                bf16x8 bv3 = *(const bf16x8*)&hpt[48 + li][mb];
                C0 = MFMA_B16(a, bv0, C0, 0, 0, 0);
                C1 = MFMA_B16(a, bv1, C1, 0, 0, 0);
                C2 = MFMA_B16(a, bv2, C2, 0, 0, 0);
                C3 = MFMA_B16(a, bv3, C3, 0, 0, 0);
            }
        }
        float inv[4];
        #pragma unroll
        for (int h = 0; h < 4; ++h) {
            if (h < nh) {
                float d = den[h];
                d += __shfl_xor(d, 16);
                d += __shfl_xor(d, 32);
                inv[h] = 1.0f / d;
            }
        }
        const int n0 = 16 * wv + 4 * lg;
        if (layer == 0) {
            #pragma unroll
            for (int c = 0; c < 4; ++c) {
                f32x4 C = (c == 0) ? C0 : (c == 1) ? C1 : (c == 2) ? C2 : C3;
                #pragma unroll
                for (int r = 0; r < 4; ++r) {
                    float iv = __shfl(inv[c], 4 * lg + r);  // lane li'=4lg+r owns row n0+r
                    float val = fmaf(C[r], iv, b0r);
                    val = (val > 0.f) ? val : (__expf(val) - 1.0f);   // ELU
                    hb[n0 + r][16 * c + li] = f2b(val);
                }
            }
            __syncthreads();
        } else {
            float* ob = out + (size_t)b * 4096;
            #pragma unroll
            for (int c = 0; c < 4; ++c) {
                f32x4 C = (c == 0) ? C0 : (c == 1) ? C1 : (c == 2) ? C2 : C3;
                #pragma unroll
                for (int r = 0; r < 4; ++r) {
                    float iv = __shfl(inv[0], 4 * lg + r);
                    ob[(n0 + r) * 64 + 16 * c + li] = fmaf(C[r], iv, b1r[c]);
                }
            }
        }
    };

    // ================= layer 0 =================
    do_matmul(0);
    // stage W1 image (wt dead until matmul1; hides under attn0)
    { int e = tid * 8;         *(uint4*)&wt[e >> 6][e & 63] = *(const uint4*)(wsb + 4608 + e); }
    { int e = (tid + 256) * 8; *(uint4*)&wt[e >> 6][e & 63] = *(const uint4*)(wsb + 4608 + e); }
    if (tid < 64) { int e = (tid + 512) * 8; *(uint4*)&wt[e >> 6][e & 63] = *(const uint4*)(wsb + 4608 + e); }
    do_attn(0);

    // ================= layer 1 =================
    do_norm1();
    do_matmul(1);
    do_attn(1);
}

extern "C" void kernel_launch(void* const* d_in, const int* in_sizes, int n_in,
                              void* d_out, int out_size, void* d_ws, size_t ws_size,
                              hipStream_t stream)
{
    const float* x   = (const float*)d_in[0];
    const int*   fhi = (const int*)d_in[1];
    const float* w0  = (const float*)d_in[2];
    const float* as0 = (const float*)d_in[3];
    const float* ad0 = (const float*)d_in[4];
    const float* b0  = (const float*)d_in[5];
    const float* w1  = (const float*)d_in[6];
    const float* as1 = (const float*)d_in[7];
    const float* ad1 = (const float*)d_in[8];
    const float* b1  = (const float*)d_in[9];
    float* o = (float*)d_out;
    unsigned short* ws = (unsigned short*)d_ws;
    hipLaunchKernelGGL(prep_weights, dim3(1), dim3(256), 0, stream,
                       w0, as0, ad0, w1, as1, ad1, ws);
    hipLaunchKernelGGL(gat_fused, dim3(8192), dim3(256), 0, stream,
                       x, fhi, ws, b0, b1, o);
}

// Round 7
// 280.219 us; speedup vs baseline: 1.0228x; 1.0228x over previous
//
#include <hip/hip_runtime.h>
#include <hip/hip_bf16.h>

// GAT encoder, fused, bf16-MFMA. B=8192 graphs, N=64, F=64. 4 waves/block,
// 6 blocks/CU (LDS 25104 B), launch_bounds(256,6).
//
// R7 vs R6 (same math, stall-bound fixes):
//  - hb+hpt merged into ONE buf[64][72]: A-frags are wave-own rows, read into
//    regs, then a barrier, then C-writes reuse the same buffer. -9216 B LDS
//    -> 6 blocks/CU (was 5).
//  - factors esp/esn in fac[64][8] f32 (1 row = 2x float4 read); edp/edn keep
//    the dsc[8][64] alias (disjoint live ranges with norm scratch).
//  - redundant norm combine: every thread computes mean/rstd for chan=lane
//    from the 8 dsc partials (saves 1 barrier + LDS writeback per norm).
//  - layer-1 norm stats computed IN the attn0 epilogue from C-frag registers
//    (shfl_xor over lg) -> the norm1 re-read pass is gone; normalize is a
//    single RMW pass over buf.
//  - W1 image: global loads issued before attn0, LDS stores after (T14).
//
// Phase/barrier map (10 barriers B0..B9):
//  stage wt0/mask/x | B0 | norm0 partials | B1 | combine+normalize->buf | B2 |
//  A-read L0 | B3 | MFMA + C->buf + factors | B4 | attn0 MFMA (+W1 ld/st) | B5 |
//  epi: ELU->buf + norm1 partials | B6 | combine + RMW normalize | B7 |
//  A-read L1 | B8 | MFMA + C->buf + factors | B9 | attn1 -> global.
//
// Softmax (unchanged): e = exp2(lrelu(s'+d')) factorized as (p>=1 ? p : esn*edn),
// p=esp*edp, log2-domain scores clamped at 63 (garbage-row guard; 63+63<128
// keeps exp2 finite so *mymask kills it exactly). Masked col m: edp=edn=0.
// Fully-masked row: e = fma(sel, 0, 1) = 1 for all m -> uniform 1/64.

typedef __attribute__((ext_vector_type(8))) short bf16x8;
typedef __attribute__((ext_vector_type(4))) float f32x4;

#define MFMA_B16 __builtin_amdgcn_mfma_f32_16x16x32_bf16

__device__ __forceinline__ unsigned short f2b(float f) {
    return __builtin_bit_cast(unsigned short, __float2bfloat16(f));
}
__device__ __forceinline__ float b2f(unsigned short s) {
    unsigned u = ((unsigned)s) << 16;
    return __builtin_bit_cast(float, u);
}

// ---- prep: per-layer 72x64 bf16 weight images in d_ws (identical to R6) ----
// L0 (ws+0):    rows 0..63 = W0^T concat ([h*16+o][f]); 64..67 = wa0[h][f];
//               68..71 = wd0[h][f]
// L1 (ws+4608): rows 0..63 = W1^T ([o][f]); 64 = wa1[f]; 65 = wd1[f]; 66..71 = 0
__global__ __launch_bounds__(256) void prep_weights(
    const float* __restrict__ w0g, const float* __restrict__ as0,
    const float* __restrict__ ad0, const float* __restrict__ w1g,
    const float* __restrict__ as1, const float* __restrict__ ad1,
    unsigned short* __restrict__ ws)
{
    const int tid = threadIdx.x;
    #pragma unroll
    for (int k = 0; k < 16; ++k) {
        int idx = k * 256 + tid;                 // w0: [4][64][16]
        int hh = idx >> 10, f = (idx >> 4) & 63, o = idx & 15;
        ws[(hh * 16 + o) * 64 + f] = f2b(w0g[idx]);
        int f1 = idx >> 6, o1 = idx & 63;        // w1: [64][64]
        ws[4608 + o1 * 64 + f1] = f2b(w1g[idx]);
    }
    if (tid < 64) {
        const int f = tid;
        #pragma unroll
        for (int h = 0; h < 4; ++h) {
            float sa = 0.f, sd = 0.f;
            #pragma unroll
            for (int o = 0; o < 16; ++o) {
                float w = w0g[(h * 64 + f) * 16 + o];
                sa = fmaf(w, as0[h * 16 + o], sa);
                sd = fmaf(w, ad0[h * 16 + o], sd);
            }
            ws[(64 + h) * 64 + f] = f2b(sa);
            ws[(68 + h) * 64 + f] = f2b(sd);
        }
        float sa = 0.f, sd = 0.f;
        #pragma unroll
        for (int o = 0; o < 64; ++o) {
            float w = w1g[f * 64 + o];
            sa = fmaf(w, as1[o], sa);
            sd = fmaf(w, ad1[o], sd);
        }
        ws[4608 + 64 * 64 + f] = f2b(sa);
        ws[4608 + 65 * 64 + f] = f2b(sd);
        for (int r = 66; r < 72; ++r) ws[4608 + r * 64 + f] = 0;
    }
}

__global__ __launch_bounds__(256, 6) void gat_fused(
    const float* __restrict__ x, const int* __restrict__ fhi,
    const unsigned short* __restrict__ wsb,
    const float* __restrict__ b0g, const float* __restrict__ b1g,
    float* __restrict__ out)
{
    const int b = blockIdx.x;
    const int scene = b >> 3;
    const int tt = b & 7;
    const int tid = threadIdx.x;
    const int lane = tid & 63;
    const int wv = tid >> 6;
    const int lg = lane >> 4;
    const int li = lane & 15;
    const int R = 16 * wv + li;          // this lane's attention/matmul row
    constexpr float L2E = 1.44269504f;

    __shared__ __align__(16) unsigned short buf[64][72];  //  9216 B (h / hp^T)
    __shared__ __align__(16) unsigned short wt [80][72];  // 11520 B
    __shared__ __align__(16) float dsc[8][64];            //  2048 B (norm scratch ALIAS edp/edn)
    __shared__ __align__(16) float fac[64][8];            //  2048 B (esp[0..3], esn[0..3] per row)
    __shared__ float maskv[64];                           //   256 B
    __shared__ float cnt4[4];                             //    16 B  -> 25104 B

    const float b0r = b0g[li];
    const float b1r0 = b1g[li], b1r1 = b1g[16 + li], b1r2 = b1g[32 + li], b1r3 = b1g[48 + li];
    const float mymask = (fhi[scene * 64 + R] <= tt) ? 1.0f : 0.0f;
    const float base = 1.0f - mymask;
    if (tid < 64) maskv[tid] = (fhi[scene * 64 + tid] <= tt) ? 1.0f : 0.0f;
    {   // visible-row count via ballot (rows duplicated 4x across lg)
        unsigned long long bal = __ballot(mymask > 0.f);
        if (lane == 0) cnt4[wv] = (float)(int)(__popcll(bal) >> 2);
    }
    if (tid < 72) {   // zero wt rows 72..79 (score B-frag overreach)
        int row = 72 + tid / 9, c8 = (tid % 9) * 8;
        *(uint4*)&wt[row][c8] = make_uint4(0, 0, 0, 0);
    }

    // ---- x into registers (rows 4k+wv, chan=lane) + stage W0 image ----
    float xv[16];
    {
        const float* xb = x + (size_t)b * 4096;
        #pragma unroll
        for (int k = 0; k < 16; ++k) xv[k] = xb[(4 * k + wv) * 64 + lane];
        { int e = tid * 8;         *(uint4*)&wt[e >> 6][e & 63] = *(const uint4*)(wsb + e); }
        { int e = (tid + 256) * 8; *(uint4*)&wt[e >> 6][e & 63] = *(const uint4*)(wsb + e); }
        if (tid < 64) { int e = (tid + 512) * 8; *(uint4*)&wt[e >> 6][e & 63] = *(const uint4*)(wsb + e); }
    }
    __syncthreads();                                   // B0
    const float invcnt = 1.0f / fmaxf(cnt4[0] + cnt4[1] + cnt4[2] + cnt4[3], 1.0f);

    // ---- norm0 partials ----
    {
        float s = 0.f, q = 0.f;
        #pragma unroll
        for (int k = 0; k < 16; ++k) {
            float mv = maskv[4 * k + wv];
            float xm = xv[k] * mv;
            s += xm;
            q = fmaf(xm, xv[k], q);
        }
        dsc[wv][lane] = s;
        dsc[4 + wv][lane] = q;
    }
    __syncthreads();                                   // B1
    {   // redundant combine (chan=lane) + normalize -> buf bf16
        float sum = dsc[0][lane] + dsc[1][lane] + dsc[2][lane] + dsc[3][lane];
        float ssq = dsc[4][lane] + dsc[5][lane] + dsc[6][lane] + dsc[7][lane];
        float mean = sum * invcnt;
        float rstd = rsqrtf(fmaxf(ssq * invcnt - mean * mean, 0.f) + 1e-5f);
        #pragma unroll
        for (int k = 0; k < 16; ++k)
            buf[4 * k + wv][lane] = f2b((xv[k] - mean) * rstd);
    }
    __syncthreads();                                   // B2

    // ---- matmul: MFMA + C->buf (hp^T) + score factors ----
    auto matmul_write = [&](int layer, bf16x8 a0, bf16x8 a1) {
        #pragma unroll
        for (int c = 0; c < 4; ++c) {
            bf16x8 bv0 = *(const bf16x8*)&wt[16 * c + li][8 * lg];
            bf16x8 bv1 = *(const bf16x8*)&wt[16 * c + li][32 + 8 * lg];
            f32x4 acc = {0.f, 0.f, 0.f, 0.f};
            acc = MFMA_B16(a0, bv0, acc, 0, 0, 0);
            acc = MFMA_B16(a1, bv1, acc, 0, 0, 0);
            ushort4 pv;
            pv.x = f2b(acc[0]); pv.y = f2b(acc[1]);
            pv.z = f2b(acc[2]); pv.w = f2b(acc[3]);
            *(ushort4*)&buf[16 * c + li][16 * wv + 4 * lg] = pv;
        }
        {   // score block -> softmax factors
            bf16x8 bv0 = *(const bf16x8*)&wt[64 + li][8 * lg];
            bf16x8 bv1 = *(const bf16x8*)&wt[64 + li][32 + 8 * lg];
            f32x4 acc = {0.f, 0.f, 0.f, 0.f};
            acc = MFMA_B16(a0, bv0, acc, 0, 0, 0);
            acc = MFMA_B16(a1, bv1, acc, 0, 0, 0);
            const int smax = (layer == 0) ? 4 : 1;
            if (li < smax) {            // src-score producer, head li
                #pragma unroll
                for (int r = 0; r < 4; ++r) {
                    int row = 16 * wv + 4 * lg + r;
                    float sl2 = fminf(acc[r] * L2E, 63.f);
                    fac[row][li]     = exp2f(sl2);
                    fac[row][4 + li] = exp2f(0.2f * sl2);
                }
            } else if (li < 2 * smax) { // dst-score producer, head li-smax
                int h = li - smax;
                #pragma unroll
                for (int r = 0; r < 4; ++r) {
                    int row = 16 * wv + 4 * lg + r;
                    float mv = maskv[row];
                    float dl2 = fminf(acc[r] * L2E, 63.f);
                    dsc[h][row]     = (mv > 0.f) ? exp2f(dl2) : 0.f;
                    dsc[4 + h][row] = (mv > 0.f) ? exp2f(0.2f * dl2) : 0.f;
                }
            }
        }
    };

    f32x4 C0, C1, C2, C3;
    float inv[4];
    auto attn_core = [&](int layer) {
        float fr[8];
        *(float4*)&fr[0] = *(const float4*)&fac[R][0];
        *(float4*)&fr[4] = *(const float4*)&fac[R][4];
        f32x4 z = {0.f, 0.f, 0.f, 0.f};
        C0 = z; C1 = z; C2 = z; C3 = z;
        float den[4] = {0.f, 0.f, 0.f, 0.f};
        #pragma unroll
        for (int t = 0; t < 2; ++t) {
            const int mb = 32 * t + 8 * lg;
            if (layer == 0) {
                #pragma unroll
                for (int h = 0; h < 4; ++h) {
                    float dpv[8], dnv[8];
                    *(float4*)&dpv[0] = *(const float4*)&dsc[h][mb];
                    *(float4*)&dpv[4] = *(const float4*)&dsc[h][mb + 4];
                    *(float4*)&dnv[0] = *(const float4*)&dsc[4 + h][mb];
                    *(float4*)&dnv[4] = *(const float4*)&dsc[4 + h][mb + 4];
                    bf16x8 a;
                    #pragma unroll
                    for (int j = 0; j < 8; ++j) {
                        float p  = fr[h]     * dpv[j];
                        float pn = fr[4 + h] * dnv[j];
                        float e = (p >= 1.0f) ? p : pn;
                        e = fmaf(e, mymask, base);
                        den[h] += e;
                        a[j] = (short)f2b(e);
                    }
                    bf16x8 bv = *(const bf16x8*)&buf[16 * h + li][mb];
                    if (h == 0) C0 = MFMA_B16(a, bv, C0, 0, 0, 0);
                    if (h == 1) C1 = MFMA_B16(a, bv, C1, 0, 0, 0);
                    if (h == 2) C2 = MFMA_B16(a, bv, C2, 0, 0, 0);
                    if (h == 3) C3 = MFMA_B16(a, bv, C3, 0, 0, 0);
                }
            } else {
                float dpv[8], dnv[8];
                *(float4*)&dpv[0] = *(const float4*)&dsc[0][mb];
                *(float4*)&dpv[4] = *(const float4*)&dsc[0][mb + 4];
                *(float4*)&dnv[0] = *(const float4*)&dsc[4][mb];
                *(float4*)&dnv[4] = *(const float4*)&dsc[4][mb + 4];
                bf16x8 a;
                #pragma unroll
                for (int j = 0; j < 8; ++j) {
                    float p  = fr[0] * dpv[j];
                    float pn = fr[4] * dnv[j];
                    float e = (p >= 1.0f) ? p : pn;
                    e = fmaf(e, mymask, base);
                    den[0] += e;
                    a[j] = (short)f2b(e);
                }
                bf16x8 bv0 = *(const bf16x8*)&buf[li][mb];
                bf16x8 bv1 = *(const bf16x8*)&buf[16 + li][mb];
                bf16x8 bv2 = *(const bf16x8*)&buf[32 + li][mb];
                bf16x8 bv3 = *(const bf16x8*)&buf[48 + li][mb];
                C0 = MFMA_B16(a, bv0, C0, 0, 0, 0);
                C1 = MFMA_B16(a, bv1, C1, 0, 0, 0);
                C2 = MFMA_B16(a, bv2, C2, 0, 0, 0);
                C3 = MFMA_B16(a, bv3, C3, 0, 0, 0);
            }
        }
        const int nh = (layer == 0) ? 4 : 1;
        #pragma unroll
        for (int h = 0; h < 4; ++h) {
            if (h < nh) {
                float d = den[h];
                d += __shfl_xor(d, 16);
                d += __shfl_xor(d, 32);
                inv[h] = 1.0f / d;
            }
        }
    };

    // ================= layer 0 =================
    {
        bf16x8 a0 = *(const bf16x8*)&buf[R][8 * lg];
        bf16x8 a1 = *(const bf16x8*)&buf[R][32 + 8 * lg];
        __syncthreads();                               // B3 (A-reads done; buf reusable)
        matmul_write(0, a0, a1);
    }
    __syncthreads();                                   // B4
    // W1 image: load early, store after attn0 (T14)
    uint4 w1a, w1b, w1c;
    { int e = tid * 8;         w1a = *(const uint4*)(wsb + 4608 + e); }
    { int e = (tid + 256) * 8; w1b = *(const uint4*)(wsb + 4608 + e); }
    if (tid < 64) { int e = (tid + 512) * 8; w1c = *(const uint4*)(wsb + 4608 + e); }
    attn_core(0);
    { int e = tid * 8;         *(uint4*)&wt[e >> 6][e & 63] = w1a; }
    { int e = (tid + 256) * 8; *(uint4*)&wt[e >> 6][e & 63] = w1b; }
    if (tid < 64) { int e = (tid + 512) * 8; *(uint4*)&wt[e >> 6][e & 63] = w1c; }
    __syncthreads();                                   // B5 (attn0 B-reads done)
    {   // epilogue: ELU -> buf (own rows) + norm1 partials from registers
        const int n0 = 16 * wv + 4 * lg;
        float m0 = maskv[n0], m1 = maskv[n0 + 1], m2 = maskv[n0 + 2], m3 = maskv[n0 + 3];
        #pragma unroll
        for (int c = 0; c < 4; ++c) {
            f32x4 C = (c == 0) ? C0 : (c == 1) ? C1 : (c == 2) ? C2 : C3;
            float vv[4];
            #pragma unroll
            for (int r = 0; r < 4; ++r) {
                float iv = __shfl(inv[c], 4 * lg + r);   // lane li'=4lg+r owns row n0+r
                float v = fmaf(C[r], iv, b0r);
                vv[r] = (v > 0.f) ? v : (__expf(v) - 1.0f);   // ELU
            }
            float s = vv[0] * m0 + vv[1] * m1 + vv[2] * m2 + vv[3] * m3;
            float q = fmaf(vv[0] * m0, vv[0], fmaf(vv[1] * m1, vv[1],
                      fmaf(vv[2] * m2, vv[2], vv[3] * m3 * vv[3])));
            s += __shfl_xor(s, 16); s += __shfl_xor(s, 32);
            q += __shfl_xor(q, 16); q += __shfl_xor(q, 32);
            if (lg == 0) { dsc[wv][16 * c + li] = s; dsc[4 + wv][16 * c + li] = q; }
            #pragma unroll
            for (int r = 0; r < 4; ++r)
                buf[n0 + r][16 * c + li] = f2b(vv[r]);
        }
    }
    __syncthreads();                                   // B6
    {   // norm1 finish: redundant combine (chan=lane) + RMW normalize
        float sum = dsc[0][lane] + dsc[1][lane] + dsc[2][lane] + dsc[3][lane];
        float ssq = dsc[4][lane] + dsc[5][lane] + dsc[6][lane] + dsc[7][lane];
        float mean = sum * invcnt;
        float rstd = rsqrtf(fmaxf(ssq * invcnt - mean * mean, 0.f) + 1e-5f);
        #pragma unroll
        for (int k = 0; k < 16; ++k) {
            int r = 4 * k + wv;
            buf[r][lane] = f2b((b2f(buf[r][lane]) - mean) * rstd);
        }
    }
    __syncthreads();                                   // B7

    // ================= layer 1 =================
    {
        bf16x8 a0 = *(const bf16x8*)&buf[R][8 * lg];
        bf16x8 a1 = *(const bf16x8*)&buf[R][32 + 8 * lg];
        __syncthreads();                               // B8 (A-reads done)
        matmul_write(1, a0, a1);
    }
    __syncthreads();                                   // B9
    attn_core(1);
    {
        const int n0 = 16 * wv + 4 * lg;
        float* ob = out + (size_t)b * 4096;
        #pragma unroll
        for (int c = 0; c < 4; ++c) {
            f32x4 C = (c == 0) ? C0 : (c == 1) ? C1 : (c == 2) ? C2 : C3;
            float bias = (c == 0) ? b1r0 : (c == 1) ? b1r1 : (c == 2) ? b1r2 : b1r3;
            #pragma unroll
            for (int r = 0; r < 4; ++r) {
                float iv = __shfl(inv[0], 4 * lg + r);
                ob[(n0 + r) * 64 + 16 * c + li] = fmaf(C[r], iv, bias);
            }
        }
    }
}

extern "C" void kernel_launch(void* const* d_in, const int* in_sizes, int n_in,
                              void* d_out, int out_size, void* d_ws, size_t ws_size,
                              hipStream_t stream)
{
    const float* x   = (const float*)d_in[0];
    const int*   fhi = (const int*)d_in[1];
    const float* w0  = (const float*)d_in[2];
    const float* as0 = (const float*)d_in[3];
    const float* ad0 = (const float*)d_in[4];
    const float* b0  = (const float*)d_in[5];
    const float* w1  = (const float*)d_in[6];
    const float* as1 = (const float*)d_in[7];
    const float* ad1 = (const float*)d_in[8];
    const float* b1  = (const float*)d_in[9];
    float* o = (float*)d_out;
    unsigned short* ws = (unsigned short*)d_ws;
    hipLaunchKernelGGL(prep_weights, dim3(1), dim3(256), 0, stream,
                       w0, as0, ad0, w1, as1, ad1, ws);
    hipLaunchKernelGGL(gat_fused, dim3(8192), dim3(256), 0, stream,
                       x, fhi, ws, b0, b1, o);
}